// Round 10
// baseline (707.965 us; speedup 1.0000x reference)
//
#include <hip/hip_runtime.h>
#include <hip/hip_bf16.h>
#include <stdint.h>

// Problem constants (from reference)
#define V_SZ 32000
#define D_SZ 1024          // = K
#define M_SZ 8192          // B*S = 4*2048

typedef __attribute__((ext_vector_type(8))) short bf16x8;
typedef __attribute__((ext_vector_type(4))) float f32x4;
typedef __attribute__((ext_vector_type(16))) float f32x16;

static __device__ __forceinline__ unsigned short f32_to_bf16_rne(float f) {
    union { float f; uint32_t u; } v; v.f = f;
    uint32_t u = v.u;
    uint32_t lsb = (u >> 16) & 1;
    u += 0x7fffu + lsb;
    return (unsigned short)(u >> 16);
}

// ---------------------------------------------------------------------------
// Kernel 1: embedding gather. One block per output row, float4 copy.
__global__ void gather_rows(const int* __restrict__ ids,
                            const float* __restrict__ table,
                            float* __restrict__ out) {
    int row = blockIdx.x;
    int id  = ids[row];
    const f32x4* src = (const f32x4*)(table + (size_t)id * D_SZ);
    f32x4*       dst = (f32x4*)(out + (size_t)row * D_SZ);
    __builtin_nontemporal_store(src[threadIdx.x], &dst[threadIdx.x]);
}

// ---------------------------------------------------------------------------
// Kernel 2: cast embeds f32 -> bf16 (A matrix [M][K]), 8 elems/thread.
__global__ void cast_f32_bf16(const float* __restrict__ in,
                              unsigned short* __restrict__ out, int n8) {
    int i = blockIdx.x * blockDim.x + threadIdx.x;
    int stride = gridDim.x * blockDim.x;
    for (; i < n8; i += stride) {
        const float4* p = (const float4*)(in + (size_t)i * 8);
        float4 a = p[0], b = p[1];
        union { unsigned short s[8]; uint4 v; } r;
        r.s[0] = f32_to_bf16_rne(a.x); r.s[1] = f32_to_bf16_rne(a.y);
        r.s[2] = f32_to_bf16_rne(a.z); r.s[3] = f32_to_bf16_rne(a.w);
        r.s[4] = f32_to_bf16_rne(b.x); r.s[5] = f32_to_bf16_rne(b.y);
        r.s[6] = f32_to_bf16_rne(b.z); r.s[7] = f32_to_bf16_rne(b.w);
        ((uint4*)out)[i] = r.v;
    }
}

// ---------------------------------------------------------------------------
// Kernel 3: transpose+cast out_weight [K=1024][V=32000] f32 -> Bt [V][K] bf16.
__global__ void transpose_cast(const float* __restrict__ w,
                               unsigned short* __restrict__ bt) {
    __shared__ unsigned short tile[32][34];
    int n0 = blockIdx.x * 32;          // column block in V
    int k0 = blockIdx.y * 32;          // row block in K
    int r = threadIdx.x >> 5;          // 0..7
    int c = threadIdx.x & 31;          // 0..31
#pragma unroll
    for (int rr = 0; rr < 32; rr += 8) {
        float v = w[(size_t)(k0 + r + rr) * V_SZ + (n0 + c)];
        tile[c][r + rr] = f32_to_bf16_rne(v);
    }
    __syncthreads();
    int nl = threadIdx.x >> 3;         // 0..31
    int ks = threadIdx.x & 7;          // 0..7  (4 bf16 = 8B per thread)
    union { unsigned short s[4]; uint2 v; } r2;
#pragma unroll
    for (int j = 0; j < 4; ++j) r2.s[j] = tile[nl][ks * 4 + j];
    ((uint2*)(bt + (size_t)(n0 + nl) * D_SZ + k0))[ks] = r2.v;
}

// ---------------------------------------------------------------------------
// Kernel 4: PERSISTENT bf16 GEMM, 256x256 tile, BK=64, 8 waves (2Mx4N),
// 32x32x16 MFMA, 128 KiB LDS dbuf, k-split layout (0 bank conflicts).
// 2 phases per K-step, no sched_barrier, no pre-MFMA barrier: compiler's
// counted lgkmcnt interleaves ds_read with MFMA. A(t+1) staged in half 1
// into the other buffer; B(t+2) staged in half 2 into the current buffer.
// vmcnt(4) at step end retires exactly tile t+1's stages.
// BUGFIX r9: prologue must stage B(1) (loop only stages B(t+2); at t=0
// that's B(2) -- B(1) was a hole -> NaN from poisoned LDS).
#define BM 256
#define BN 256
#define BK 64
#define NSTEP (D_SZ / BK)   // 16 K-steps per tile

static __device__ __forceinline__ void gload_lds16(const unsigned short* g, void* lds) {
    __builtin_amdgcn_global_load_lds(
        (const __attribute__((address_space(1))) void*)g,
        (__attribute__((address_space(3))) void*)lds,
        16, 0, 0);
}

__global__ __launch_bounds__(512, 2)
void gemm_persist(const unsigned short* __restrict__ A,
                  const unsigned short* __restrict__ Bt,
                  float* __restrict__ C) {
    __shared__ __align__(16) char lds[131072];

    const int tid  = threadIdx.x;
    const int lane = tid & 63;
    const int w    = tid >> 6;           // wave 0..7
    const int wr   = w >> 2;             // 0..1  (A half)
    const int wc   = w & 3;              // 0..3  (B: half = wc>>1, sub = wc&1)

    // bid&7 = XCD. Fixed bm per block (2 MB A slice/XCD, L2-pinned); bn
    // tile = q0 + 8r swept in cross-XCD lockstep (L3 serves each B panel ~once).
    const int bid = blockIdx.x;
    const int xcd = bid & 7;
    const int jb  = bid >> 3;            // 0..31
    const int bm0 = (xcd * 4 + (jb & 3)) * BM;
    const int q0  = jb >> 2;             // 0..7
    const int ntiles = (bid < 160) ? 16 : 15;

    // staging thread mapping: (hi0,row0) and (hi0+4,row0)
    const int hi0  = tid >> 7;           // 0..3
    const int row0 = tid & 127;          // 0..127
    const int dstO = hi0 * 2048 + row0 * 16;
    const unsigned short* gA  = A  + (size_t)(bm0 + row0) * D_SZ + hi0 * 8;  // rows 0-127
    const unsigned short* gA1 = gA + (size_t)128 * D_SZ;                     // rows 128-255
    const unsigned short* gBc = Bt + (size_t)(q0 * BN + row0) * D_SZ + hi0 * 8;
    const size_t bn_stride = (size_t)8 * BN * D_SZ;   // bn advances 8 tiles per r

#define STG(ptr, slotbase) do { \
    gload_lds16((ptr),      (char*)lds + (slotbase) + dstO); \
    gload_lds16((ptr) + 32, (char*)lds + (slotbase) + dstO + 8192); } while (0)

    // Prologue: tile0 step0 fully into buf0 + B(1) into buf1; drain; barrier.
    STG(gA,                                 0);
    STG(gA1,                                16384);
    STG(gBc,                                32768);
    STG(gBc + (size_t)128 * D_SZ,           49152);
    STG(gBc + 64,                           65536 + 32768);
    STG(gBc + (size_t)128 * D_SZ + 64,      65536 + 49152);
    asm volatile("s_waitcnt vmcnt(0)" ::: "memory");
    __builtin_amdgcn_s_barrier();

    f32x16 acc[4][2];
#pragma unroll
    for (int m = 0; m < 4; ++m)
#pragma unroll
        for (int n = 0; n < 2; ++n)
#pragma unroll
            for (int e = 0; e < 16; ++e) acc[m][n][e] = 0.0f;

    bf16x8 a[2][4];       // [mi2][kk] current QM quadrant (regs reused across halves)
    bf16x8 b[2][4];       // [qn][kk]  both QN quadrants (live whole step)

    // 32x32x16 frag: row/col = lane&31, k-group = kk*2 + (lane>>5)
    const int base_f = (lane >> 5) * 2048 + (lane & 31) * 16;

#define LDA(mi2, kk, QM) (*(const bf16x8*)(abuf + (kk) * 4096 + ((QM) * 2 + (mi2)) * 512 + base_f))
#define LDB(ni, kk)      (*(const bf16x8*)(bbuf + (kk) * 4096 + (ni) * 512 + base_f))

#define MFMA_Q(QM, QN) \
    _Pragma("unroll") for (int kk = 0; kk < 4; ++kk) \
    _Pragma("unroll") for (int mi2 = 0; mi2 < 2; ++mi2) \
        acc[(QM) * 2 + mi2][QN] = __builtin_amdgcn_mfma_f32_32x32x16_bf16( \
            a[mi2][kk], b[QN][kk], acc[(QM) * 2 + mi2][QN], 0, 0, 0);

    const int crow = bm0 + wr * 128 + (lane >> 5) * 4;
    const int ccol_f = wc * 64 + (lane & 31);

    for (int r = 0; r < ntiles; ++r) {
        const unsigned short* gBn = gBc + bn_stride;
        const bool last = (r == ntiles - 1);

        for (int t = 0; t < NSTEP; ++t) {
            const int   dbuf  = (t & 1) << 16;
            const int   nslot = dbuf ^ 65536;
            const char* abuf  = (const char*)lds + dbuf + wr * 16384;
            const char* bbuf  = (const char*)lds + dbuf + 32768
                                + (wc >> 1) * 16384 + (wc & 1) * 1024;

            // ---- Half 1: reads A_QM0 + B0 + B1; stage A(t+1) both halves;
            //      MFMA (0,0),(0,1); barrier.
            a[0][0] = LDA(0, 0, 0); a[0][1] = LDA(0, 1, 0);
            a[0][2] = LDA(0, 2, 0); a[0][3] = LDA(0, 3, 0);
            a[1][0] = LDA(1, 0, 0); a[1][1] = LDA(1, 1, 0);
            a[1][2] = LDA(1, 2, 0); a[1][3] = LDA(1, 3, 0);
            b[0][0] = LDB(0, 0); b[0][1] = LDB(0, 1);
            b[0][2] = LDB(0, 2); b[0][3] = LDB(0, 3);
            b[1][0] = LDB(1, 0); b[1][1] = LDB(1, 1);
            b[1][2] = LDB(1, 2); b[1][3] = LDB(1, 3);
            if (!(last && t == 15)) {
                STG(gA  + ((t + 1) & 15) * 64, nslot);
                STG(gA1 + ((t + 1) & 15) * 64, nslot + 16384);
            }
            __builtin_amdgcn_s_setprio(1);
            MFMA_Q(0, 0);
            MFMA_Q(0, 1);
            __builtin_amdgcn_s_setprio(0);
            __builtin_amdgcn_s_barrier();

            // ---- Half 2: reads A_QM1 (reuse a regs); stage B(t+2);
            //      MFMA (1,1),(1,0); counted vmcnt; barrier.
            a[0][0] = LDA(0, 0, 1); a[0][1] = LDA(0, 1, 1);
            a[0][2] = LDA(0, 2, 1); a[0][3] = LDA(0, 3, 1);
            a[1][0] = LDA(1, 0, 1); a[1][1] = LDA(1, 1, 1);
            a[1][2] = LDA(1, 2, 1); a[1][3] = LDA(1, 3, 1);
            if (t < 14 || !last) {
                const unsigned short* pb = (t < 14) ? gBc + (t + 2) * 64
                                                    : gBn + (t - 14) * 64;
                STG(pb, dbuf + 32768);
                STG(pb + (size_t)128 * D_SZ, dbuf + 49152);
            }
            __builtin_amdgcn_s_setprio(1);
            MFMA_Q(1, 1);
            MFMA_Q(1, 0);
            __builtin_amdgcn_s_setprio(0);
            if (last && t >= 14) { asm volatile("s_waitcnt vmcnt(0)" ::: "memory"); }
            else                 { asm volatile("s_waitcnt vmcnt(4)" ::: "memory"); }
            __builtin_amdgcn_s_barrier();
        }

        // Epilogue for tile r (in-flight staging for tile r+1 continues).
        // 32x32 C frag: col = lane&31, row = (e&3) + 8*(e>>2) + 4*(lane>>5).
        const int ccol = (q0 + 8 * r) * BN + ccol_f;
#pragma unroll
        for (int mi = 0; mi < 4; ++mi)
#pragma unroll
            for (int ni = 0; ni < 2; ++ni) {
                float* base = C + (size_t)(crow + mi * 32) * V_SZ + (ccol + ni * 32);
#pragma unroll
                for (int e = 0; e < 16; ++e) {
                    int roff = (e & 3) + 8 * (e >> 2);
                    __builtin_nontemporal_store(acc[mi][ni][e], base + (size_t)roff * V_SZ);
                }
            }
#pragma unroll
        for (int m = 0; m < 4; ++m)
#pragma unroll
            for (int n = 0; n < 2; ++n)
#pragma unroll
                for (int e = 0; e < 16; ++e) acc[m][n][e] = 0.0f;

        gBc = gBn;
    }
#undef STG
#undef LDA
#undef LDB
#undef MFMA_Q
}

// ---------------------------------------------------------------------------
extern "C" void kernel_launch(void* const* d_in, const int* in_sizes, int n_in,
                              void* d_out, int out_size, void* d_ws, size_t ws_size,
                              hipStream_t stream) {
    const int*   ids        = (const int*)d_in[0];       // [B,S] = 8192
    const float* embeds     = (const float*)d_in[1];     // [B,S,D]
    const float* in_weight  = (const float*)d_in[2];     // [V,D]
    const float* out_weight = (const float*)d_in[3];     // [D,V]

    float* out_embedded = (float*)d_out;                       // M*D floats
    float* out_logits   = (float*)d_out + (size_t)M_SZ * D_SZ; // M*V floats

    // workspace: A bf16 [M][K] (16 MB) + Bt bf16 [V][K] (64 MB) = ~82 MB
    unsigned short* Abf  = (unsigned short*)d_ws;
    unsigned short* Btbf = Abf + (size_t)M_SZ * D_SZ;

    gather_rows<<<M_SZ, 256, 0, stream>>>(ids, in_weight, out_embedded);
    cast_f32_bf16<<<2048, 256, 0, stream>>>(embeds, Abf, M_SZ * D_SZ / 8);
    transpose_cast<<<dim3(V_SZ / 32, D_SZ / 32), 256, 0, stream>>>(out_weight, Btbf);
    gemm_persist<<<dim3(256), 512, 0, stream>>>(Abf, Btbf, out_logits);
}